// Round 2
// baseline (1390.671 us; speedup 1.0000x reference)
//
#include <hip/hip_runtime.h>
#include <stdint.h>

typedef unsigned short u16;
typedef __attribute__((ext_vector_type(8))) short short8;
typedef __attribute__((ext_vector_type(4))) float floatx4;
typedef __attribute__((ext_vector_type(4))) int intx4;

// Problem constants: B=8, NQ=NK=1024, D_MODEL=1024, H=16, D_K=D_V=64

__device__ __forceinline__ u16 f2bf(float f) {
  uint32_t u = __float_as_uint(f);
  u = (u + 0x7fffu + ((u >> 16) & 1u)) >> 16;   // RNE
  return (u16)u;
}

__device__ __forceinline__ void gl_lds16(const void* g, void* l) {
  __builtin_amdgcn_global_load_lds(
      (__attribute__((address_space(1))) void*)g,
      (__attribute__((address_space(3))) void*)l, 16, 0, 0);
}

// ---------------- fp32 -> bf16 conversion (8 elems/thread) ----------------
__global__ __launch_bounds__(256) void cvt_bf16(const float* __restrict__ src,
                                                u16* __restrict__ dst, int n8) {
  int i = blockIdx.x * 256 + threadIdx.x;
  if (i >= n8) return;
  const float4 a = ((const float4*)src)[i * 2];
  const float4 b = ((const float4*)src)[i * 2 + 1];
  short8 o;
  o[0] = (short)f2bf(a.x); o[1] = (short)f2bf(a.y);
  o[2] = (short)f2bf(a.z); o[3] = (short)f2bf(a.w);
  o[4] = (short)f2bf(b.x); o[5] = (short)f2bf(b.y);
  o[6] = (short)f2bf(b.z); o[7] = (short)f2bf(b.w);
  ((short8*)dst)[i] = o;
}

// ---------------- bf16 GEMM: C[M,N] = A[M,K] @ B[N,K]^T + bias ----------------
// m97 structure upgraded to 2-phase counted-vmcnt pipeline (T3/T4 minimum form):
// double-buffered LDS, stage(t+1) issued before compute(t), raw s_barrier
// (no compiler vmcnt(0) drain), s_waitcnt vmcnt(4) keeps next tile in flight.
// mode 0: out fp32 row-major. mode 1: out bf16 (b,h,n,d). mode 2: bf16 (b,h,d,n).
__global__ __launch_bounds__(256) void gemm_bt(
    const u16* __restrict__ A, const u16* __restrict__ Bm,
    const float* __restrict__ bias, float* __restrict__ outF,
    u16* __restrict__ outB, int M, int N, int K, float scale, int mode) {
  __shared__ u16 As[2][4096];
  __shared__ u16 Bs[2][4096];
  const int tid = threadIdx.x;
  const int wid = tid >> 6, lane = tid & 63;
  const int lane15 = lane & 15, quad = lane >> 4;
  const int m0 = blockIdx.y * 128, n0 = blockIdx.x * 128;
  const int wm = (wid >> 1) * 64, wn = (wid & 1) * 64;
  const int srow = tid >> 2;
  const int scol = (tid & 3) * 8;

  floatx4 acc[4][4];
#pragma unroll
  for (int i = 0; i < 4; i++)
#pragma unroll
    for (int j = 0; j < 4; j++) acc[i][j] = floatx4{0.f, 0.f, 0.f, 0.f};

  auto stage = [&](int k0, u16* As_, u16* Bs_) {
    gl_lds16(A + (size_t)(m0 + srow) * K + k0 + scol, As_ + tid * 8);
    gl_lds16(A + (size_t)(m0 + 64 + srow) * K + k0 + scol, As_ + 2048 + tid * 8);
    gl_lds16(Bm + (size_t)(n0 + srow) * K + k0 + scol, Bs_ + tid * 8);
    gl_lds16(Bm + (size_t)(n0 + 64 + srow) * K + k0 + scol, Bs_ + 2048 + tid * 8);
  };
  auto compute = [&](const u16* As_, const u16* Bs_) {
    short8 af[4], bf[4];
#pragma unroll
    for (int i = 0; i < 4; i++)
      af[i] = *(const short8*)(As_ + (wm + i * 16 + lane15) * 32 + quad * 8);
#pragma unroll
    for (int j = 0; j < 4; j++)
      bf[j] = *(const short8*)(Bs_ + (wn + j * 16 + lane15) * 32 + quad * 8);
#pragma unroll
    for (int i = 0; i < 4; i++)
#pragma unroll
      for (int j = 0; j < 4; j++)
        acc[i][j] = __builtin_amdgcn_mfma_f32_16x16x32_bf16(af[i], bf[j], acc[i][j], 0, 0, 0);
  };

  stage(0, As[0], Bs[0]);
  for (int k0 = 0; k0 < K; k0 += 64) {
    stage(k0 + 32, As[1], Bs[1]);
    asm volatile("s_waitcnt vmcnt(4)" ::: "memory");
    __builtin_amdgcn_sched_barrier(0);
    __builtin_amdgcn_s_barrier();
    __builtin_amdgcn_sched_barrier(0);
    compute(As[0], Bs[0]);
    __builtin_amdgcn_s_barrier();
    int kn = k0 + 64; if (kn >= K) kn = 0;   // wrap dummy keeps vmcnt uniform
    stage(kn, As[0], Bs[0]);
    asm volatile("s_waitcnt vmcnt(4)" ::: "memory");
    __builtin_amdgcn_sched_barrier(0);
    __builtin_amdgcn_s_barrier();
    __builtin_amdgcn_sched_barrier(0);
    compute(As[1], Bs[1]);
    __builtin_amdgcn_s_barrier();
  }

  const int NQ = 1024;
#pragma unroll
  for (int j = 0; j < 4; j++) {
    const int col = n0 + wn + j * 16 + lane15;
    const float bv = bias[col];
#pragma unroll
    for (int i = 0; i < 4; i++) {
      if (mode == 2) {
        const int rowb = m0 + wm + i * 16 + quad * 4;
        const int b_ = rowb >> 10, n_ = rowb & 1023;
        const int h_ = col >> 6, d_ = col & 63;
        u16 pk[4];
#pragma unroll
        for (int r = 0; r < 4; r++) pk[r] = f2bf((acc[i][j][r] + bv) * scale);
        u16* dp = outB + (((size_t)b_ * 16 + h_) * 64 + d_) * (size_t)NQ + n_;
        *(uint2*)dp = *(const uint2*)pk;
      } else {
#pragma unroll
        for (int r = 0; r < 4; r++) {
          const int row = m0 + wm + i * 16 + quad * 4 + r;
          const float v = (acc[i][j][r] + bv) * scale;
          if (mode == 0) {
            outF[(size_t)row * N + col] = v;
          } else {
            const int b_ = row >> 10, n_ = row & 1023;
            const int h_ = col >> 6, d_ = col & 63;
            outB[(((size_t)b_ * 16 + h_) * NQ + n_) * 64 + d_] = f2bf(v);
          }
        }
      }
    }
  }
}

// ---------------- fused flash attention, S^T formulation ----------------
// grid (B*H, NQ/128); block 256 = 4 waves; wave owns 32 q-rows.
// v2: K/V staged in LDS via global_load_lds (block-shared, XOR-swizzled via
// pre-swizzled SOURCE per T2/rule-21), consumed via ds_read (lgkmcnt) — off
// the vmcnt path. W/M stream register-double-buffered. Per body: issue
// [4 KV stages + 16 W/M loads for tile t+1], then counted s_waitcnt vmcnt(20)
// + raw s_barrier: tile t+1's 20 loads stay in flight across the whole body.
__global__ __launch_bounds__(256, 2) void attn(
    const u16* __restrict__ Qp, const u16* __restrict__ Kp,
    const u16* __restrict__ Vt, const float* __restrict__ Wgt,
    const int* __restrict__ Msk, u16* __restrict__ AO) {
  __shared__ u16 Ps[4][32 * 72];
  __shared__ u16 Kb[2][4096];   // 64 keys x 64 d, 16B-chunk XOR-swizzled rows
  __shared__ u16 Vb[2][4096];   // 64 d x 64 keys, same swizzle
  const int bh = blockIdx.x;
  const int qb = blockIdx.y;
  const int tid = threadIdx.x;
  const int wid = tid >> 6, lane = tid & 63;
  const int lane15 = lane & 15, quad = lane >> 4;
  const int l7 = lane15 & 7;
  const int qbase = qb * 128 + wid * 32;

  const u16* Qh = Qp + ((size_t)bh * 1024 + qbase) * 64;
  const u16* Kh = Kp + (size_t)bh * 1024 * 64;
  const u16* Vh = Vt + (size_t)bh * 64 * 1024;
  const float* Wr = Wgt + (size_t)bh * 1024 * 1024 + (size_t)(qbase + lane15) * 1024;
  const int*   Mr = Msk + (size_t)bh * 1024 * 1024 + (size_t)(qbase + lane15) * 1024;

  // Q fragments (B-operand: n=lane15=qrow, k=quad*8+j), loop-invariant
  short8 qf[2][2];
#pragma unroll
  for (int qt = 0; qt < 2; qt++)
#pragma unroll
    for (int ks = 0; ks < 2; ks++)
      qf[qt][ks] = *(const short8*)(Qh + (size_t)(qt * 16 + lane15) * 64 + ks * 32 + quad * 8);

  // Stage K/V tile (64 keys / all 64 d) into LDS. LDS dest is linear
  // (wave base + lane*16B); the SOURCE 16B-chunk index is XOR'd with the
  // destination row (rule 21), so LDS[row][j] = src[row][j ^ (row&7)].
  const int lr = lane >> 3;                 // dest row within instr (0..7)
  const int cs = (lane & 7) ^ (lr & 7);     // pre-swizzled source chunk
  auto stageKV = [&](int kcn, u16* Kb_, u16* Vb_) {
#pragma unroll
    for (int s = 0; s < 2; s++) {
      const int row = wid * 16 + s * 8 + lr;   // 0..63
      gl_lds16(Kh + (size_t)(kcn + row) * 64 + cs * 8, Kb_ + wid * 1024 + s * 512 + lane * 8);
      gl_lds16(Vh + (size_t)row * 1024 + kcn + cs * 8, Vb_ + wid * 1024 + s * 512 + lane * 8);
    }
  };

  // W/M double buffers (named A/B — static indexing only, rule #20)
  floatx4 wA[2][4], wB[2][4];
  intx4   mA[2][4], mB[2][4];
  auto loadWM = [&](int kcc, floatx4 (&w)[2][4], intx4 (&m)[2][4]) {
#pragma unroll
    for (int qt = 0; qt < 2; qt++)
#pragma unroll
      for (int kt = 0; kt < 4; kt++) {
        const int off = qt * 16 * 1024 + kcc + kt * 16 + quad * 4;
        w[qt][kt] = __builtin_nontemporal_load((const floatx4*)(Wr + off));
        m[qt][kt] = __builtin_nontemporal_load((const intx4*)(Mr + off));
      }
  };

  float mrun[2] = {-1e30f, -1e30f};
  float lrun[2] = {0.f, 0.f};
  floatx4 oacc[2][4];
#pragma unroll
  for (int mt = 0; mt < 2; mt++)
#pragma unroll
    for (int nt = 0; nt < 4; nt++) oacc[mt][nt] = floatx4{0.f, 0.f, 0.f, 0.f};

  auto body = [&](int kc, const u16* Kb_, const u16* Vb_,
                  const floatx4 (&w4)[2][4], const intx4 (&m4)[2][4]) {
    __builtin_amdgcn_wave_barrier();

    // phase B: S^T = K Q^T from LDS (swizzled read)
    floatx4 sacc[4][2];
#pragma unroll
    for (int kt = 0; kt < 4; kt++)
#pragma unroll
      for (int qt = 0; qt < 2; qt++) sacc[kt][qt] = floatx4{0.f, 0.f, 0.f, 0.f};
#pragma unroll
    for (int ks = 0; ks < 2; ks++) {
#pragma unroll
      for (int kt = 0; kt < 4; kt++) {
        short8 kf = *(const short8*)(Kb_ + (kt * 16 + lane15) * 64 + ((ks * 4 + quad) ^ l7) * 8);
        sacc[kt][0] = __builtin_amdgcn_mfma_f32_16x16x32_bf16(kf, qf[0][ks], sacc[kt][0], 0, 0, 0);
        sacc[kt][1] = __builtin_amdgcn_mfma_f32_16x16x32_bf16(kf, qf[1][ks], sacc[kt][1], 0, 0, 0);
      }
    }

    // phase C: weights, mask, online softmax
    float alpha[2];
#pragma unroll
    for (int qt = 0; qt < 2; qt++) {
#pragma unroll
      for (int kt = 0; kt < 4; kt++)
#pragma unroll
        for (int r = 0; r < 4; r++)
          sacc[kt][qt][r] = m4[qt][kt][r] ? -1e30f : sacc[kt][qt][r] * w4[qt][kt][r];

      float mkt[4];
#pragma unroll
      for (int kt = 0; kt < 4; kt++)
        mkt[kt] = fmaxf(fmaxf(sacc[kt][qt][0], sacc[kt][qt][1]),
                        fmaxf(sacc[kt][qt][2], sacc[kt][qt][3]));
      float mx = fmaxf(fmaxf(mkt[0], mkt[1]), fmaxf(mkt[2], mkt[3]));
      mx = fmaxf(mx, __shfl_xor(mx, 16));
      mx = fmaxf(mx, __shfl_xor(mx, 32));

      const float mnew = fmaxf(mrun[qt], mx);
      alpha[qt] = __expf(mrun[qt] - mnew);
      mrun[qt] = mnew;

      float pskt[4];
#pragma unroll
      for (int kt = 0; kt < 4; kt++) {
        u16 pk[4];
        float s0 = 0.f, s1 = 0.f;
#pragma unroll
        for (int r = 0; r < 4; r++) {
          const float p = __expf(sacc[kt][qt][r] - mnew);
          if (r & 1) s1 += p; else s0 += p;
          pk[r] = f2bf(p);
        }
        pskt[kt] = s0 + s1;
        const uint32_t lo = (uint32_t)pk[0] | ((uint32_t)pk[1] << 16);
        const uint32_t hi = (uint32_t)pk[2] | ((uint32_t)pk[3] << 16);
        uint2 pv; pv.x = lo; pv.y = hi;
        *(uint2*)&Ps[wid][(qt * 16 + lane15) * 72 + kt * 16 + quad * 4] = pv;
      }
      float ps = (pskt[0] + pskt[1]) + (pskt[2] + pskt[3]);
      ps += __shfl_xor(ps, 16);
      ps += __shfl_xor(ps, 32);
      lrun[qt] = lrun[qt] * alpha[qt] + ps;
    }

    __builtin_amdgcn_wave_barrier();

    // phase D: broadcast alpha into O C-layout rows, rescale O
#pragma unroll
    for (int mt = 0; mt < 2; mt++)
#pragma unroll
      for (int r = 0; r < 4; r++) {
        const float als = __shfl(alpha[mt], quad * 4 + r);
#pragma unroll
        for (int nt = 0; nt < 4; nt++) oacc[mt][nt][r] *= als;
      }

    // phase E: O += P V   (A=P from LDS, B=V from swizzled LDS)
#pragma unroll
    for (int ks = 0; ks < 2; ks++) {
      short8 pf[2];
#pragma unroll
      for (int mt = 0; mt < 2; mt++)
        pf[mt] = *(const short8*)&Ps[wid][(mt * 16 + lane15) * 72 + ks * 32 + quad * 8];
#pragma unroll
      for (int nt = 0; nt < 4; nt++) {
        short8 vf = *(const short8*)(Vb_ + (nt * 16 + lane15) * 64 + ((ks * 4 + quad) ^ l7) * 8);
        oacc[0][nt] = __builtin_amdgcn_mfma_f32_16x16x32_bf16(pf[0], vf, oacc[0][nt], 0, 0, 0);
        oacc[1][nt] = __builtin_amdgcn_mfma_f32_16x16x32_bf16(pf[1], vf, oacc[1][nt], 0, 0, 0);
      }
    }
  };

  // prologue: tile 0's 20 loads in flight
  stageKV(0, Kb[0], Vb[0]);
  loadWM(0, wA, mA);

  // main loop, unrolled 2x for static buffer names.
  // Per half-iter: issue t+1's 20 loads, wait vmcnt(20) (t's done, t+1 in
  // flight), raw barrier (all waves' stages landed), compute t, barrier (WAR).
  for (int it = 0; it < 16; it += 2) {
    const int kc0 = it << 6, kc1 = kc0 + 64;
    stageKV(kc1, Kb[1], Vb[1]);
    loadWM(kc1, wB, mB);
    asm volatile("s_waitcnt vmcnt(20)" ::: "memory");
    __builtin_amdgcn_sched_barrier(0);
    __builtin_amdgcn_s_barrier();
    __builtin_amdgcn_sched_barrier(0);
    body(kc0, Kb[0], Vb[0], wA, mA);
    __builtin_amdgcn_s_barrier();

    const int kcn = (kc0 + 128) & 1023;   // wraps to 0 on last trip (dummy)
    stageKV(kcn, Kb[0], Vb[0]);
    loadWM(kcn, wA, mA);
    asm volatile("s_waitcnt vmcnt(20)" ::: "memory");
    __builtin_amdgcn_sched_barrier(0);
    __builtin_amdgcn_s_barrier();
    __builtin_amdgcn_sched_barrier(0);
    body(kc1, Kb[1], Vb[1], wB, mB);
    __builtin_amdgcn_s_barrier();
  }

  // epilogue: O / l -> AO (b, q, h*64+d) bf16
  const int b_ = bh >> 4, h_ = bh & 15;
#pragma unroll
  for (int mt = 0; mt < 2; mt++)
#pragma unroll
    for (int r = 0; r < 4; r++) {
      const float ls = __shfl(lrun[mt], quad * 4 + r);
      const float inv_l = 1.f / ls;
      const int row = qbase + mt * 16 + quad * 4 + r;
#pragma unroll
      for (int nt = 0; nt < 4; nt++) {
        const int col = nt * 16 + lane15;
        AO[((size_t)b_ * 1024 + row) * 1024 + h_ * 64 + col] = f2bf(oacc[mt][nt][r] * inv_l);
      }
    }
}

extern "C" void kernel_launch(void* const* d_in, const int* in_sizes, int n_in,
                              void* d_out, int out_size, void* d_ws, size_t ws_size,
                              hipStream_t stream) {
  const float* queries = (const float*)d_in[0];
  const float* keys    = (const float*)d_in[1];
  const float* values  = (const float*)d_in[2];
  const int*   mask    = (const int*)d_in[3];
  const float* weights = (const float*)d_in[4];
  const float* Wq = (const float*)d_in[5];
  const float* bq = (const float*)d_in[6];
  const float* Wk = (const float*)d_in[7];
  const float* bk = (const float*)d_in[8];
  const float* Wv = (const float*)d_in[9];
  const float* bv = (const float*)d_in[10];
  const float* Wo = (const float*)d_in[11];
  const float* bo = (const float*)d_in[12];
  float* out = (float*)d_out;

  char* ws = (char*)d_ws;
  const size_t MB = 1024 * 1024;
  u16* qb  = (u16*)(ws + 0 * MB);
  u16* kb  = (u16*)(ws + 16 * MB);
  u16* vb  = (u16*)(ws + 32 * MB);
  u16* wqb = (u16*)(ws + 48 * MB);
  u16* wkb = (u16*)(ws + 50 * MB);
  u16* wvb = (u16*)(ws + 52 * MB);
  u16* wob = (u16*)(ws + 54 * MB);
  u16* Qp  = (u16*)(ws + 56 * MB);   // (B*H,1024,64) bf16, pre-scaled by 1/8
  u16* Kp  = (u16*)(ws + 72 * MB);   // (B*H,1024,64)
  u16* Vt  = (u16*)(ws + 88 * MB);   // (B*H,64,1024)
  u16* AO  = (u16*)(ws + 104 * MB);  // (B,1024,1024) bf16

  cvt_bf16<<<4096, 256, 0, stream>>>(queries, qb, 8388608 / 8);
  cvt_bf16<<<4096, 256, 0, stream>>>(keys, kb, 8388608 / 8);
  cvt_bf16<<<4096, 256, 0, stream>>>(values, vb, 8388608 / 8);
  cvt_bf16<<<512, 256, 0, stream>>>(Wq, wqb, 1048576 / 8);
  cvt_bf16<<<512, 256, 0, stream>>>(Wk, wkb, 1048576 / 8);
  cvt_bf16<<<512, 256, 0, stream>>>(Wv, wvb, 1048576 / 8);
  cvt_bf16<<<512, 256, 0, stream>>>(Wo, wob, 1048576 / 8);

  dim3 gg(1024 / 128, 8192 / 128);
  gemm_bt<<<gg, 256, 0, stream>>>(qb, wqb, bq, nullptr, Qp, 8192, 1024, 1024, 0.125f, 1);
  gemm_bt<<<gg, 256, 0, stream>>>(kb, wkb, bk, nullptr, Kp, 8192, 1024, 1024, 1.0f, 1);
  gemm_bt<<<gg, 256, 0, stream>>>(vb, wvb, bv, nullptr, Vt, 8192, 1024, 1024, 1.0f, 2);

  attn<<<dim3(128, 8), 256, 0, stream>>>(Qp, Kp, Vt, weights, mask, AO);

  gemm_bt<<<gg, 256, 0, stream>>>(AO, wob, bo, out, nullptr, 8192, 1024, 1024, 1.0f, 0);
}

// Round 3
// 1249.072 us; speedup vs baseline: 1.1134x; 1.1134x over previous
//
#include <hip/hip_runtime.h>
#include <stdint.h>

typedef unsigned short u16;
typedef __attribute__((ext_vector_type(8))) short short8;
typedef __attribute__((ext_vector_type(4))) float floatx4;
typedef __attribute__((ext_vector_type(4))) int intx4;

// Problem constants: B=8, NQ=NK=1024, D_MODEL=1024, H=16, D_K=D_V=64

__device__ __forceinline__ u16 f2bf(float f) {
  uint32_t u = __float_as_uint(f);
  u = (u + 0x7fffu + ((u >> 16) & 1u)) >> 16;   // RNE
  return (u16)u;
}

__device__ __forceinline__ void gl_lds16(const void* g, void* l) {
  __builtin_amdgcn_global_load_lds(
      (__attribute__((address_space(1))) void*)g,
      (__attribute__((address_space(3))) void*)l, 16, 0, 0);
}

// asm global load: keeps loop VMEM off the compiler's waitcnt bookkeeping.
// Completion is guaranteed ONLY after a manual s_waitcnt vmcnt(N).
__device__ __forceinline__ intx4 gload16(const void* p) {
  intx4 r;
  asm volatile("global_load_dwordx4 %0, %1, off" : "=v"(r) : "v"(p) : "memory");
  return r;
}

// ---------------- fp32 -> bf16 conversion (8 elems/thread) ----------------
__global__ __launch_bounds__(256) void cvt_bf16(const float* __restrict__ src,
                                                u16* __restrict__ dst, int n8) {
  int i = blockIdx.x * 256 + threadIdx.x;
  if (i >= n8) return;
  const float4 a = ((const float4*)src)[i * 2];
  const float4 b = ((const float4*)src)[i * 2 + 1];
  short8 o;
  o[0] = (short)f2bf(a.x); o[1] = (short)f2bf(a.y);
  o[2] = (short)f2bf(a.z); o[3] = (short)f2bf(a.w);
  o[4] = (short)f2bf(b.x); o[5] = (short)f2bf(b.y);
  o[6] = (short)f2bf(b.z); o[7] = (short)f2bf(b.w);
  ((short8*)dst)[i] = o;
}

// ---------------- bf16 GEMM: C[M,N] = A[M,K] @ B[N,K]^T + bias ----------------
// Catalog-minimal 2-phase: stage(t+1) issued BEFORE compute(t); ONE
// __syncthreads per K-step (its vmcnt0 drain is the pipeline boundary).
// XCD swizzle: the 8 n0-blocks sharing an A-panel land on one XCD's L2.
// mode 0: out fp32 row-major. mode 1: out bf16 (b,h,n,d). mode 2: bf16 (b,h,d,n).
__global__ __launch_bounds__(256) void gemm_bt(
    const u16* __restrict__ A, const u16* __restrict__ Bm,
    const float* __restrict__ bias, float* __restrict__ outF,
    u16* __restrict__ outB, int M, int N, int K, float scale, int mode) {
  __shared__ u16 As0[4096], Bs0[4096], As1[4096], Bs1[4096];
  const int tid = threadIdx.x;
  const int wid = tid >> 6, lane = tid & 63;
  const int lane15 = lane & 15, quad = lane >> 4;
  int bx = blockIdx.x, by = blockIdx.y;
  if (gridDim.x == 8 && gridDim.y == 64) {           // bijective XCD swizzle
    const int lin = by * 8 + bx;
    bx = lin >> 6;
    by = ((lin & 7) << 3) | ((lin >> 3) & 7);
  }
  const int m0 = by * 128, n0 = bx * 128;
  const int wm = (wid >> 1) * 64, wn = (wid & 1) * 64;
  const int srow = tid >> 2;
  const int scol = (tid & 3) * 8;

  floatx4 acc[4][4];
#pragma unroll
  for (int i = 0; i < 4; i++)
#pragma unroll
    for (int j = 0; j < 4; j++) acc[i][j] = floatx4{0.f, 0.f, 0.f, 0.f};

  auto stage = [&](int k0, u16* As_, u16* Bs_) {
    gl_lds16(A + (size_t)(m0 + srow) * K + k0 + scol, As_ + tid * 8);
    gl_lds16(A + (size_t)(m0 + 64 + srow) * K + k0 + scol, As_ + 2048 + tid * 8);
    gl_lds16(Bm + (size_t)(n0 + srow) * K + k0 + scol, Bs_ + tid * 8);
    gl_lds16(Bm + (size_t)(n0 + 64 + srow) * K + k0 + scol, Bs_ + 2048 + tid * 8);
  };
  auto compute = [&](const u16* As_, const u16* Bs_) {
    short8 af[4], bf[4];
#pragma unroll
    for (int i = 0; i < 4; i++)
      af[i] = *(const short8*)(As_ + (wm + i * 16 + lane15) * 32 + quad * 8);
#pragma unroll
    for (int j = 0; j < 4; j++)
      bf[j] = *(const short8*)(Bs_ + (wn + j * 16 + lane15) * 32 + quad * 8);
#pragma unroll
    for (int i = 0; i < 4; i++)
#pragma unroll
      for (int j = 0; j < 4; j++)
        acc[i][j] = __builtin_amdgcn_mfma_f32_16x16x32_bf16(af[i], bf[j], acc[i][j], 0, 0, 0);
  };

  stage(0, As0, Bs0);
  __syncthreads();
  for (int k0 = 0; k0 < K; k0 += 64) {
    stage(k0 + 32, As1, Bs1);       // in flight across compute(t)
    compute(As0, Bs0);
    __syncthreads();                 // drains stage(t+1), WAR-protects As0
    if (k0 + 64 < K) stage(k0 + 64, As0, Bs0);
    compute(As1, Bs1);
    __syncthreads();
  }

  const int NQ = 1024;
#pragma unroll
  for (int j = 0; j < 4; j++) {
    const int col = n0 + wn + j * 16 + lane15;
    const float bv = bias[col];
#pragma unroll
    for (int i = 0; i < 4; i++) {
      if (mode == 2) {
        const int rowb = m0 + wm + i * 16 + quad * 4;
        const int b_ = rowb >> 10, n_ = rowb & 1023;
        const int h_ = col >> 6, d_ = col & 63;
        u16 pk[4];
#pragma unroll
        for (int r = 0; r < 4; r++) pk[r] = f2bf((acc[i][j][r] + bv) * scale);
        u16* dp = outB + (((size_t)b_ * 16 + h_) * 64 + d_) * (size_t)NQ + n_;
        *(uint2*)dp = *(const uint2*)pk;
      } else {
#pragma unroll
        for (int r = 0; r < 4; r++) {
          const int row = m0 + wm + i * 16 + quad * 4 + r;
          const float v = (acc[i][j][r] + bv) * scale;
          if (mode == 0) {
            outF[(size_t)row * N + col] = v;
          } else {
            const int b_ = row >> 10, n_ = row & 1023;
            const int h_ = col >> 6, d_ = col & 63;
            outB[(((size_t)b_ * 16 + h_) * NQ + n_) * 64 + d_] = f2bf(v);
          }
        }
      }
    }
  }
}

// ---------------- fused flash attention, S^T formulation, v3 ----------------
// grid (B*H, NQ/128); block 256 = 4 waves; wave owns 32 q-rows; 32-key tiles.
// Key change: W/M (the 1.07 GB single-use stream) staged per-wave into LDS
// via global_load_lds with LINE-COALESCED source mapping (each 1KB instr =
// 4 rows x 256B), double-buffered; consumed via swizzled ds_read_b128
// (conflict-free). K/V/Q are inline-asm loads (no compiler vmcnt waits);
// K/V register-double-buffered one tile ahead. ONE counted s_waitcnt
// vmcnt(16) per half-iter; NO s_barrier in the loop (all wave-private).
__global__ __launch_bounds__(256, 2) void attn(
    const u16* __restrict__ Qp, const u16* __restrict__ Kp,
    const u16* __restrict__ Vt, const float* __restrict__ Wgt,
    const int* __restrict__ Msk, u16* __restrict__ AO) {
  __shared__ __align__(16) char WM[4][2][8192];   // per wave: [buf][W 4KB | M 4KB]
  __shared__ u16 Ps[4][32 * 40];                  // 80B rows: 16B-aligned b128 reads
  const int bh = blockIdx.x;
  const int qb = blockIdx.y;
  const int tid = threadIdx.x;
  const int wid = tid >> 6, lane = tid & 63;
  const int lane15 = lane & 15, quad = lane >> 4;
  const int qbase = qb * 128 + wid * 32;

  const u16* Qh = Qp + ((size_t)bh * 1024 + qbase) * 64;
  const u16* Kh = Kp + (size_t)bh * 1024 * 64;
  const u16* Vh = Vt + (size_t)bh * 64 * 1024;
  const float* Wb = Wgt + (size_t)bh * 1048576 + (size_t)qbase * 1024;
  const int*   Mb = Msk + (size_t)bh * 1048576 + (size_t)qbase * 1024;

  char* wm0 = &WM[wid][0][0];
  char* wm1 = &WM[wid][1][0];
  u16*  PsW = &Ps[wid][0];

  // W/M staging: instr ib covers rows ib*8..ib*8+7, each row = 128B (32 floats).
  // Source chunk XOR-swizzled with row-in-instr (rule 21 both-sides involution).
  const int lr = lane >> 3;              // row-in-instr 0..7
  const int lc = (lane & 7) ^ lr;        // swizzled 16B-chunk 0..7
  auto stageWM = [&](int kc, char* dst) {
#pragma unroll
    for (int ib = 0; ib < 4; ib++) {
      const int row = ib * 8 + lr;
      gl_lds16(Wb + (size_t)row * 1024 + kc + lc * 4, dst + ib * 1024 + lane * 16);
      gl_lds16(Mb + (size_t)row * 1024 + kc + lc * 4, dst + 4096 + ib * 1024 + lane * 16);
    }
  };

  // K/V register double buffers (tile = 32 keys).
  intx4 kA[4], vA[4], kB[4], vB[4];
  auto loadK = [&](int kc, intx4 (&kd)[4]) {
#pragma unroll
    for (int kt = 0; kt < 2; kt++)
#pragma unroll
      for (int ks = 0; ks < 2; ks++)
        kd[kt * 2 + ks] = gload16(Kh + (size_t)(kc + kt * 16 + lane15) * 64 + ks * 32 + quad * 8);
  };
  auto loadV = [&](int kc, intx4 (&vd)[4]) {
#pragma unroll
    for (int nt = 0; nt < 4; nt++)
      vd[nt] = gload16(Vh + (size_t)(nt * 16 + lane15) * 1024 + kc + quad * 8);
  };

  // prologue: WM tiles 0,1; KV tile 0; Q frags — all asm/builtin, one drain.
  stageWM(0, wm0);
  stageWM(32, wm1);
  loadK(0, kA);
  loadV(0, vA);
  intx4 qi[4];
#pragma unroll
  for (int qt = 0; qt < 2; qt++)
#pragma unroll
    for (int ks = 0; ks < 2; ks++)
      qi[qt * 2 + ks] = gload16(Qh + (size_t)(qt * 16 + lane15) * 64 + ks * 32 + quad * 8);
  asm volatile("s_waitcnt vmcnt(0)" ::: "memory");
  __builtin_amdgcn_sched_barrier(0);
  short8 qf[2][2];
#pragma unroll
  for (int qt = 0; qt < 2; qt++)
#pragma unroll
    for (int ks = 0; ks < 2; ks++)
      qf[qt][ks] = *(const short8*)&qi[qt * 2 + ks];

  float mrun[2] = {-1e30f, -1e30f};
  float lrun[2] = {0.f, 0.f};
  floatx4 oacc[2][4];
#pragma unroll
  for (int mt = 0; mt < 2; mt++)
#pragma unroll
    for (int nt = 0; nt < 4; nt++) oacc[mt][nt] = floatx4{0.f, 0.f, 0.f, 0.f};

  // one half-iteration: tile t (32 keys at kc), WM in wmCur, K/V in kC/vC.
  // Prefetches: WM(t+2)->wmCur (after its reads), KV(t+1)->kN/vN.
  auto halfiter = [&](int kc, char* wmCur, int kcPre, int kcKV,
                      intx4 (&kC)[4], intx4 (&vC)[4],
                      intx4 (&kN)[4], intx4 (&vN)[4]) {
    __builtin_amdgcn_wave_barrier();

    // step 1: read this tile's W/M fragments from LDS (swizzled, conflict-free)
    floatx4 wv[2][2];
    intx4   mv[2][2];
#pragma unroll
    for (int qt = 0; qt < 2; qt++) {
      const int r32 = qt * 16 + lane15;
      const int ib = r32 >> 3, r7 = r32 & 7;
#pragma unroll
      for (int kt = 0; kt < 2; kt++) {
        const int li = (r7 << 3) | ((kt * 4 + quad) ^ r7);
        wv[qt][kt] = *(const floatx4*)(wmCur + ib * 1024 + li * 16);
        mv[qt][kt] = *(const intx4*)(wmCur + 4096 + ib * 1024 + li * 16);
      }
    }
    asm volatile("s_waitcnt lgkmcnt(0)" ::: "memory");
    __builtin_amdgcn_sched_barrier(0);

    // step 2: prefetch WM(t+2) into the buffer we just finished reading
    stageWM(kcPre, wmCur);
    // step 3: prefetch KV(t+1) into the other register set
    loadK(kcKV, kN);
    loadV(kcKV, vN);
    // step 4: tile t's KV (issued last half-iter) retired; 16 newest stay in flight
    asm volatile("s_waitcnt vmcnt(16)" ::: "memory");
    __builtin_amdgcn_sched_barrier(0);

    // phase B: S^T = K Q^T
    floatx4 sacc[2][2];
#pragma unroll
    for (int kt = 0; kt < 2; kt++)
#pragma unroll
      for (int qt = 0; qt < 2; qt++) sacc[kt][qt] = floatx4{0.f, 0.f, 0.f, 0.f};
#pragma unroll
    for (int ks = 0; ks < 2; ks++)
#pragma unroll
      for (int kt = 0; kt < 2; kt++) {
        const short8 kf = *(const short8*)&kC[kt * 2 + ks];
        sacc[kt][0] = __builtin_amdgcn_mfma_f32_16x16x32_bf16(kf, qf[0][ks], sacc[kt][0], 0, 0, 0);
        sacc[kt][1] = __builtin_amdgcn_mfma_f32_16x16x32_bf16(kf, qf[1][ks], sacc[kt][1], 0, 0, 0);
      }

    // phase C: weights, mask, online softmax
    float alpha[2];
#pragma unroll
    for (int qt = 0; qt < 2; qt++) {
#pragma unroll
      for (int kt = 0; kt < 2; kt++)
#pragma unroll
        for (int r = 0; r < 4; r++)
          sacc[kt][qt][r] = mv[qt][kt][r] ? -1e30f : sacc[kt][qt][r] * wv[qt][kt][r];

      float m0_ = fmaxf(fmaxf(sacc[0][qt][0], sacc[0][qt][1]),
                        fmaxf(sacc[0][qt][2], sacc[0][qt][3]));
      float m1_ = fmaxf(fmaxf(sacc[1][qt][0], sacc[1][qt][1]),
                        fmaxf(sacc[1][qt][2], sacc[1][qt][3]));
      float mx = fmaxf(m0_, m1_);
      mx = fmaxf(mx, __shfl_xor(mx, 16));
      mx = fmaxf(mx, __shfl_xor(mx, 32));

      const float mnew = fmaxf(mrun[qt], mx);
      alpha[qt] = __expf(mrun[qt] - mnew);
      mrun[qt] = mnew;

      float ps = 0.f;
#pragma unroll
      for (int kt = 0; kt < 2; kt++) {
        u16 pk[4];
#pragma unroll
        for (int r = 0; r < 4; r++) {
          const float p = __expf(sacc[kt][qt][r] - mnew);
          ps += p;
          pk[r] = f2bf(p);
        }
        uint2 pv;
        pv.x = (uint32_t)pk[0] | ((uint32_t)pk[1] << 16);
        pv.y = (uint32_t)pk[2] | ((uint32_t)pk[3] << 16);
        *(uint2*)&PsW[(qt * 16 + lane15) * 40 + kt * 16 + quad * 4] = pv;
      }
      ps += __shfl_xor(ps, 16);
      ps += __shfl_xor(ps, 32);
      lrun[qt] = lrun[qt] * alpha[qt] + ps;
    }

    __builtin_amdgcn_wave_barrier();

    // phase D: rescale O
#pragma unroll
    for (int mt = 0; mt < 2; mt++)
#pragma unroll
      for (int r = 0; r < 4; r++) {
        const float als = __shfl(alpha[mt], quad * 4 + r);
#pragma unroll
        for (int nt = 0; nt < 4; nt++) oacc[mt][nt][r] *= als;
      }

    // phase E: O += P V (k-dim = 32, single step)
    const short8 pf0 = *(const short8*)&PsW[lane15 * 40 + quad * 8];
    const short8 pf1 = *(const short8*)&PsW[(16 + lane15) * 40 + quad * 8];
#pragma unroll
    for (int nt = 0; nt < 4; nt++) {
      const short8 vf = *(const short8*)&vC[nt];
      oacc[0][nt] = __builtin_amdgcn_mfma_f32_16x16x32_bf16(pf0, vf, oacc[0][nt], 0, 0, 0);
      oacc[1][nt] = __builtin_amdgcn_mfma_f32_16x16x32_bf16(pf1, vf, oacc[1][nt], 0, 0, 0);
    }
  };

  // 32 tiles of 32 keys, unrolled 2x for static buffer/reg names.
  for (int t = 0; t < 32; t += 2) {
    const int kc0 = t << 5, kc1 = kc0 + 32;
    halfiter(kc0, wm0, (kc0 + 64) & 1023, kc1, kA, vA, kB, vB);
    halfiter(kc1, wm1, (kc1 + 64) & 1023, (kc0 + 64) & 1023, kB, vB, kA, vA);
  }

  // epilogue: O / l -> AO (b, q, h*64+d) bf16
  const int b_ = bh >> 4, h_ = bh & 15;
#pragma unroll
  for (int mt = 0; mt < 2; mt++)
#pragma unroll
    for (int r = 0; r < 4; r++) {
      const float ls = __shfl(lrun[mt], quad * 4 + r);
      const float inv_l = 1.f / ls;
      const int row = qbase + mt * 16 + quad * 4 + r;
#pragma unroll
      for (int nt = 0; nt < 4; nt++) {
        const int col = nt * 16 + lane15;
        AO[((size_t)b_ * 1024 + row) * 1024 + h_ * 64 + col] = f2bf(oacc[mt][nt][r] * inv_l);
      }
    }
}

extern "C" void kernel_launch(void* const* d_in, const int* in_sizes, int n_in,
                              void* d_out, int out_size, void* d_ws, size_t ws_size,
                              hipStream_t stream) {
  const float* queries = (const float*)d_in[0];
  const float* keys    = (const float*)d_in[1];
  const float* values  = (const float*)d_in[2];
  const int*   mask    = (const int*)d_in[3];
  const float* weights = (const float*)d_in[4];
  const float* Wq = (const float*)d_in[5];
  const float* bq = (const float*)d_in[6];
  const float* Wk = (const float*)d_in[7];
  const float* bk = (const float*)d_in[8];
  const float* Wv = (const float*)d_in[9];
  const float* bv = (const float*)d_in[10];
  const float* Wo = (const float*)d_in[11];
  const float* bo = (const float*)d_in[12];
  float* out = (float*)d_out;

  char* ws = (char*)d_ws;
  const size_t MB = 1024 * 1024;
  u16* qb  = (u16*)(ws + 0 * MB);
  u16* kb  = (u16*)(ws + 16 * MB);
  u16* vb  = (u16*)(ws + 32 * MB);
  u16* wqb = (u16*)(ws + 48 * MB);
  u16* wkb = (u16*)(ws + 50 * MB);
  u16* wvb = (u16*)(ws + 52 * MB);
  u16* wob = (u16*)(ws + 54 * MB);
  u16* Qp  = (u16*)(ws + 56 * MB);   // (B*H,1024,64) bf16, pre-scaled by 1/8
  u16* Kp  = (u16*)(ws + 72 * MB);   // (B*H,1024,64)
  u16* Vt  = (u16*)(ws + 88 * MB);   // (B*H,64,1024)
  u16* AO  = (u16*)(ws + 104 * MB);  // (B,1024,1024) bf16

  cvt_bf16<<<4096, 256, 0, stream>>>(queries, qb, 8388608 / 8);
  cvt_bf16<<<4096, 256, 0, stream>>>(keys, kb, 8388608 / 8);
  cvt_bf16<<<4096, 256, 0, stream>>>(values, vb, 8388608 / 8);
  cvt_bf16<<<512, 256, 0, stream>>>(Wq, wqb, 1048576 / 8);
  cvt_bf16<<<512, 256, 0, stream>>>(Wk, wkb, 1048576 / 8);
  cvt_bf16<<<512, 256, 0, stream>>>(Wv, wvb, 1048576 / 8);
  cvt_bf16<<<512, 256, 0, stream>>>(Wo, wob, 1048576 / 8);

  dim3 gg(1024 / 128, 8192 / 128);
  gemm_bt<<<gg, 256, 0, stream>>>(qb, wqb, bq, nullptr, Qp, 8192, 1024, 1024, 0.125f, 1);
  gemm_bt<<<gg, 256, 0, stream>>>(kb, wkb, bk, nullptr, Kp, 8192, 1024, 1024, 1.0f, 1);
  gemm_bt<<<gg, 256, 0, stream>>>(vb, wvb, bv, nullptr, Vt, 8192, 1024, 1024, 1.0f, 2);

  attn<<<dim3(128, 8), 256, 0, stream>>>(Qp, Kp, Vt, weights, mask, AO);

  gemm_bt<<<gg, 256, 0, stream>>>(AO, wob, bo, out, nullptr, 8192, 1024, 1024, 1.0f, 0);
}